// Round 1
// baseline (778.788 us; speedup 1.0000x reference)
//
#include <hip/hip_runtime.h>
#include <math.h>

// ---------------------------------------------------------------------------
// 2-layer GCN (PyG GCNConv semantics) on MI355X.
// out[i] = dinv[i] * ( sum_{e:dst=i} g[src_e] + g[i] ) + b,  g = (x@W)*dinv
// Self-loop handled by initializing the accumulator with g[i].
// ---------------------------------------------------------------------------

#define F_IN   128
#define F_HID  32
#define F_OUT  7

__global__ void k_deg(const int* __restrict__ dst, int E, float* __restrict__ deg) {
    int e = blockIdx.x * blockDim.x + threadIdx.x;
    if (e < E) atomicAdd(&deg[dst[e]], 1.0f);
}

__global__ void k_dinv(float* __restrict__ deg, int n) {
    int i = blockIdx.x * blockDim.x + threadIdx.x;
    if (i < n) deg[i] = rsqrtf(deg[i] + 1.0f);  // +1 for self-loop; deg>=1 always
}

// GEMM1: g1[i][f] = dinv[i] * sum_k x[i][k]*W1[k][f]; also acc1 init = g1.
// Block = 256 threads = 8 rows x 32 feats. W1 (16KB) + 8 x-rows (4KB) in LDS.
__global__ void k_gemm1(const float* __restrict__ x, const float* __restrict__ W1,
                        const float* __restrict__ dinv, float* __restrict__ g1,
                        float* __restrict__ acc1, int n) {
    __shared__ float sW[F_IN * F_HID];
    __shared__ float sx[8][F_IN];
    int t = threadIdx.x;
    for (int i = t; i < F_IN * F_HID; i += 256) sW[i] = W1[i];
    int row0 = blockIdx.x * 8;
    for (int i = t; i < 8 * F_IN; i += 256) {
        int r = i >> 7, c = i & 127;
        int gr = row0 + r;
        sx[r][c] = (gr < n) ? x[(long long)gr * F_IN + c] : 0.0f;
    }
    __syncthreads();
    int r = t >> 5;   // 0..7
    int f = t & 31;   // 0..31
    int gr = row0 + r;
    if (gr < n) {
        float acc = 0.0f;
        #pragma unroll
        for (int k = 0; k < F_IN; ++k) acc += sx[r][k] * sW[k * F_HID + f];
        float v = acc * dinv[gr];
        g1[gr * F_HID + f]   = v;
        acc1[gr * F_HID + f] = v;  // self-loop term
    }
}

// Edge scatter, layer 1: acc1[dst] += g1[src], 32 floats/edge.
__global__ void k_scatter1(const int* __restrict__ src, const int* __restrict__ dst,
                           const float* __restrict__ g1, float* __restrict__ acc1,
                           int E) {
    int tid = blockIdx.x * blockDim.x + threadIdx.x;  // E*32 = 102.4M < 2^31
    if (tid < E * F_HID) {
        int e = tid >> 5;
        int f = tid & 31;
        int s = src[e], d = dst[e];
        atomicAdd(&acc1[d * F_HID + f], g1[s * F_HID + f]);
    }
}

// Finish conv1 (relu(dinv*acc1+b1)), GEMM2, scale by dinv; acc2 init = g2.
__global__ void k_layer2(const float* __restrict__ acc1, const float* __restrict__ dinv,
                         const float* __restrict__ b1, const float* __restrict__ W2,
                         float* __restrict__ g2, float* __restrict__ acc2, int n) {
    __shared__ float sW[F_HID * F_OUT];
    __shared__ float sb[F_HID];
    int t = threadIdx.x;
    if (t < F_HID * F_OUT) sW[t] = W2[t];
    if (t < F_HID) sb[t] = b1[t];
    __syncthreads();
    int i = blockIdx.x * blockDim.x + t;
    if (i < n) {
        float di = dinv[i];
        float h[F_HID];
        #pragma unroll
        for (int f = 0; f < F_HID; ++f) {
            float v = di * acc1[i * F_HID + f] + sb[f];
            h[f] = v > 0.0f ? v : 0.0f;
        }
        #pragma unroll
        for (int c = 0; c < F_OUT; ++c) {
            float a = 0.0f;
            #pragma unroll
            for (int f = 0; f < F_HID; ++f) a += h[f] * sW[f * F_OUT + c];
            float v = a * di;
            g2[i * F_OUT + c]   = v;
            acc2[i * F_OUT + c] = v;  // self-loop term
        }
    }
}

// Edge scatter, layer 2: acc2[dst] += g2[src], 7 floats/edge (8 lanes, 1 idle).
__global__ void k_scatter2(const int* __restrict__ src, const int* __restrict__ dst,
                           const float* __restrict__ g2, float* __restrict__ acc2,
                           int E) {
    int tid = blockIdx.x * blockDim.x + threadIdx.x;  // E*8 = 25.6M
    int e = tid >> 3;
    int c = tid & 7;
    if (e < E && c < F_OUT) {
        int s = src[e], d = dst[e];
        atomicAdd(&acc2[d * F_OUT + c], g2[s * F_OUT + c]);
    }
}

// Finalize: v = dinv*acc2 + b2, then row log_softmax over 7 classes.
__global__ void k_final(const float* __restrict__ acc2, const float* __restrict__ dinv,
                        const float* __restrict__ b2, float* __restrict__ out, int n) {
    int i = blockIdx.x * blockDim.x + threadIdx.x;
    if (i < n) {
        float di = dinv[i];
        float v[F_OUT];
        float m = -1e30f;
        #pragma unroll
        for (int c = 0; c < F_OUT; ++c) {
            v[c] = di * acc2[i * F_OUT + c] + b2[c];
            m = fmaxf(m, v[c]);
        }
        float s = 0.0f;
        #pragma unroll
        for (int c = 0; c < F_OUT; ++c) s += __expf(v[c] - m);
        float ls = __logf(s) + m;
        #pragma unroll
        for (int c = 0; c < F_OUT; ++c) out[i * F_OUT + c] = v[c] - ls;
    }
}

extern "C" void kernel_launch(void* const* d_in, const int* in_sizes, int n_in,
                              void* d_out, int out_size, void* d_ws, size_t ws_size,
                              hipStream_t stream) {
    const float* x   = (const float*)d_in[0];
    const int*   ei  = (const int*)d_in[1];
    const float* W1  = (const float*)d_in[2];
    const float* b1  = (const float*)d_in[3];
    const float* W2  = (const float*)d_in[4];
    const float* b2  = (const float*)d_in[5];
    float* out = (float*)d_out;

    int n = in_sizes[0] / F_IN;        // 100000
    int E = in_sizes[1] / 2;           // 3200000
    const int* src = ei;
    const int* dst = ei + E;

    // workspace layout (floats)
    float* ws   = (float*)d_ws;
    float* dinv = ws;                       // [n]   (deg, then dinv in place)
    float* g1   = dinv + n;                 // [n*32]
    float* acc1 = g1 + (size_t)n * F_HID;   // [n*32]
    float* g2   = acc1 + (size_t)n * F_HID; // [n*7]
    float* acc2 = g2 + (size_t)n * F_OUT;   // [n*7]

    hipMemsetAsync(dinv, 0, (size_t)n * sizeof(float), stream);

    k_deg<<<(E + 255) / 256, 256, 0, stream>>>(dst, E, dinv);
    k_dinv<<<(n + 255) / 256, 256, 0, stream>>>(dinv, n);
    k_gemm1<<<(n + 7) / 8, 256, 0, stream>>>(x, W1, dinv, g1, acc1, n);
    {
        long long work = (long long)E * F_HID;
        k_scatter1<<<(int)((work + 255) / 256), 256, 0, stream>>>(src, dst, g1, acc1, E);
    }
    k_layer2<<<(n + 255) / 256, 256, 0, stream>>>(acc1, dinv, b1, W2, g2, acc2, n);
    {
        long long work = (long long)E * 8;
        k_scatter2<<<(int)((work + 255) / 256), 256, 0, stream>>>(src, dst, g2, acc2, E);
    }
    k_final<<<(n + 255) / 256, 256, 0, stream>>>(acc2, dinv, b2, out, n);
}

// Round 2
// 690.521 us; speedup vs baseline: 1.1278x; 1.1278x over previous
//
#include <hip/hip_runtime.h>
#include <math.h>

// ---------------------------------------------------------------------------
// 2-layer GCN (PyG GCNConv semantics) on MI355X — CSR gather version.
// out[i] = logsoftmax( dinv[i]*(g2[i] + sum_{e:dst=i} g2[src_e]) + b2 )
// g2 = dinv * ( relu( dinv*(g1[i] + sum g1[src]) + b1 ) @ W2 ),  g1 = (x@W1)*dinv
// Self-loops handled by initializing register accumulators with own row.
// Scatter-atomics replaced by counting-sort CSR + register gather.
// ---------------------------------------------------------------------------

#define F_IN   128
#define F_HID  32
#define F_OUT  7
#define SCAN_B 512

__global__ void k_degcount(const int* __restrict__ dst, int E, int* __restrict__ degi) {
    int e = blockIdx.x * blockDim.x + threadIdx.x;
    if (e < E) atomicAdd(&degi[dst[e]], 1);
}

__global__ void k_dinv(const int* __restrict__ degi, float* __restrict__ dinv, int n) {
    int i = blockIdx.x * blockDim.x + threadIdx.x;
    if (i < n) dinv[i] = rsqrtf((float)degi[i] + 1.0f);  // +1 self-loop
}

// --- 3-kernel exclusive scan of degi -> cursor (start offsets) ---
__global__ void k_scan1(const int* __restrict__ degi, int n, int* __restrict__ bsum) {
    __shared__ int s[SCAN_B];
    int t = threadIdx.x;
    int idx = blockIdx.x * SCAN_B + t;
    s[t] = (idx < n) ? degi[idx] : 0;
    __syncthreads();
    for (int off = SCAN_B / 2; off > 0; off >>= 1) {
        if (t < off) s[t] += s[t + off];
        __syncthreads();
    }
    if (t == 0) bsum[blockIdx.x] = s[0];
}

__global__ void k_scan2(int* __restrict__ bsum, int nb) {
    if (blockIdx.x == 0 && threadIdx.x == 0) {
        int run = 0;
        for (int i = 0; i < nb; ++i) { int v = bsum[i]; bsum[i] = run; run += v; }
    }
}

__global__ void k_scan3(const int* __restrict__ degi, const int* __restrict__ bsum,
                        int n, int* __restrict__ cursor) {
    __shared__ int s[SCAN_B];
    int t = threadIdx.x;
    int idx = blockIdx.x * SCAN_B + t;
    int v = (idx < n) ? degi[idx] : 0;
    s[t] = v;
    __syncthreads();
    for (int off = 1; off < SCAN_B; off <<= 1) {
        int add = (t >= off) ? s[t - off] : 0;
        __syncthreads();
        s[t] += add;
        __syncthreads();
    }
    if (idx < n) cursor[idx] = bsum[blockIdx.x] + s[t] - v;  // exclusive prefix
}

// Place src indices bucketed by dst. cursor bumps from start to end;
// afterwards cursor[i] == end(i), so start(i) = cursor[i] - degi[i].
__global__ void k_fill(const int* __restrict__ src, const int* __restrict__ dst,
                       int E, int* __restrict__ cursor, int* __restrict__ srcSorted) {
    int e = blockIdx.x * blockDim.x + threadIdx.x;
    if (e < E) {
        int pos = atomicAdd(&cursor[dst[e]], 1);
        srcSorted[pos] = src[e];
    }
}

// GEMM1: g1[i][f] = dinv[i] * sum_k x[i][k]*W1[k][f].
// Block = 256 threads = 8 rows x 32 feats. W1 (16KB) + 8 x-rows (4KB) in LDS.
__global__ void k_gemm1(const float* __restrict__ x, const float* __restrict__ W1,
                        const float* __restrict__ dinv, float* __restrict__ g1, int n) {
    __shared__ float sW[F_IN * F_HID];
    __shared__ float sx[8][F_IN];
    int t = threadIdx.x;
    for (int i = t; i < F_IN * F_HID; i += 256) sW[i] = W1[i];
    int row0 = blockIdx.x * 8;
    for (int i = t; i < 8 * F_IN; i += 256) {
        int r = i >> 7, c = i & 127;
        int gr = row0 + r;
        sx[r][c] = (gr < n) ? x[(long long)gr * F_IN + c] : 0.0f;
    }
    __syncthreads();
    int r = t >> 5;
    int f = t & 31;
    int gr = row0 + r;
    if (gr < n) {
        float acc = 0.0f;
        #pragma unroll
        for (int k = 0; k < F_IN; ++k) acc += sx[r][k] * sW[k * F_HID + f];
        g1[gr * F_HID + f] = acc * dinv[gr];
    }
}

// Gather conv1 + ReLU + tiny GEMM2 fused. 32 lanes per node, 8 nodes/block.
// Each lane f accumulates feature f in a register over the node's CSR edges,
// then h=relu(dinv*acc+b1) and a width-32 shfl butterfly reduces h[f]*W2[f][c]
// into the 7 outputs; lane 0 stores the padded row (stride 8, 32B aligned).
__global__ void k_gather1l2(const float* __restrict__ g1, const int* __restrict__ srcSorted,
                            const int* __restrict__ cursor, const int* __restrict__ degi,
                            const float* __restrict__ dinv, const float* __restrict__ b1,
                            const float* __restrict__ W2, float* __restrict__ g2p, int n) {
    int t = threadIdx.x;
    int lane = t & 31;
    int node = blockIdx.x * 8 + (t >> 5);
    if (node >= n) return;
    float w2r[F_OUT];
    #pragma unroll
    for (int c = 0; c < F_OUT; ++c) w2r[c] = W2[lane * F_OUT + c];
    int deg = degi[node];
    int end = cursor[node];
    int start = end - deg;
    float acc = g1[node * F_HID + lane];  // self-loop init
    for (int j = start; j < end; ++j) {
        int s = srcSorted[j];             // same addr across the 32-lane group
        acc += g1[s * F_HID + lane];      // 128B coalesced line per group
    }
    float di = dinv[node];
    float h = di * acc + b1[lane];
    h = h > 0.0f ? h : 0.0f;
    float p0 = h * w2r[0], p1 = h * w2r[1], p2 = h * w2r[2], p3 = h * w2r[3];
    float p4 = h * w2r[4], p5 = h * w2r[5], p6 = h * w2r[6];
    #pragma unroll
    for (int m = 1; m < 32; m <<= 1) {
        p0 += __shfl_xor(p0, m, 64);
        p1 += __shfl_xor(p1, m, 64);
        p2 += __shfl_xor(p2, m, 64);
        p3 += __shfl_xor(p3, m, 64);
        p4 += __shfl_xor(p4, m, 64);
        p5 += __shfl_xor(p5, m, 64);
        p6 += __shfl_xor(p6, m, 64);
    }
    if (lane == 0) {
        float4 q0 = make_float4(di * p0, di * p1, di * p2, di * p3);
        float4 q1 = make_float4(di * p4, di * p5, di * p6, 0.0f);
        *(float4*)&g2p[node * 8]     = q0;
        *(float4*)&g2p[node * 8 + 4] = q1;
    }
}

// Gather conv2 + bias + log-softmax fused. 8 lanes per node, 32 nodes/block.
__global__ void k_gather2final(const float* __restrict__ g2p, const int* __restrict__ srcSorted,
                               const int* __restrict__ cursor, const int* __restrict__ degi,
                               const float* __restrict__ dinv, const float* __restrict__ b2,
                               float* __restrict__ out, int n) {
    int t = threadIdx.x;
    int c = t & 7;
    int node = blockIdx.x * 32 + (t >> 3);
    if (node >= n) return;
    int deg = degi[node];
    int end = cursor[node];
    int start = end - deg;
    float acc = g2p[node * 8 + c];        // self-loop init (pad col = 0)
    for (int j = start; j < end; ++j) {
        int s = srcSorted[j];
        acc += g2p[s * 8 + c];            // 32B aligned chunk per group
    }
    float v = dinv[node] * acc + ((c < F_OUT) ? b2[c] : -1e30f);
    float m = v;
    #pragma unroll
    for (int msk = 1; msk < 8; msk <<= 1) m = fmaxf(m, __shfl_xor(m, msk, 64));
    float ex = __expf(v - m);
    float ssum = ex;
    #pragma unroll
    for (int msk = 1; msk < 8; msk <<= 1) ssum += __shfl_xor(ssum, msk, 64);
    float ls = __logf(ssum) + m;
    if (c < F_OUT) out[node * F_OUT + c] = v - ls;
}

extern "C" void kernel_launch(void* const* d_in, const int* in_sizes, int n_in,
                              void* d_out, int out_size, void* d_ws, size_t ws_size,
                              hipStream_t stream) {
    const float* x  = (const float*)d_in[0];
    const int*   ei = (const int*)d_in[1];
    const float* W1 = (const float*)d_in[2];
    const float* b1 = (const float*)d_in[3];
    const float* W2 = (const float*)d_in[4];
    const float* b2 = (const float*)d_in[5];
    float* out = (float*)d_out;

    int n = in_sizes[0] / F_IN;   // 100000
    int E = in_sizes[1] / 2;      // 3200000
    const int* src = ei;
    const int* dst = ei + E;
    int nb = (n + SCAN_B - 1) / SCAN_B;

    // workspace layout
    int*   degi      = (int*)d_ws;                    // [n]
    int*   cursor    = degi + n;                      // [n]
    int*   srcSorted = cursor + n;                    // [E]
    float* dinv      = (float*)(srcSorted + E);       // [n]
    float* g1        = dinv + n;                      // [n*32]
    float* g2p       = g1 + (size_t)n * F_HID;        // [n*8]
    int*   bsum      = (int*)(g2p + (size_t)n * 8);   // [nb]

    hipMemsetAsync(degi, 0, (size_t)n * sizeof(int), stream);

    k_degcount<<<(E + 255) / 256, 256, 0, stream>>>(dst, E, degi);
    k_dinv<<<(n + 255) / 256, 256, 0, stream>>>(degi, dinv, n);
    k_scan1<<<nb, SCAN_B, 0, stream>>>(degi, n, bsum);
    k_scan2<<<1, 64, 0, stream>>>(bsum, nb);
    k_scan3<<<nb, SCAN_B, 0, stream>>>(degi, bsum, n, cursor);
    k_fill<<<(E + 255) / 256, 256, 0, stream>>>(src, dst, E, cursor, srcSorted);
    k_gemm1<<<(n + 7) / 8, 256, 0, stream>>>(x, W1, dinv, g1, n);
    k_gather1l2<<<(n + 7) / 8, 256, 0, stream>>>(g1, srcSorted, cursor, degi, dinv, b1, W2, g2p, n);
    k_gather2final<<<(n + 31) / 32, 256, 0, stream>>>(g2p, srcSorted, cursor, degi, dinv, b2, out, n);
}